// Round 4
// baseline (225.179 us; speedup 1.0000x reference)
//
#include <hip/hip_runtime.h>
#include <hip/hip_bf16.h>

// bmm [16,256,512] @ [16,512,2048] -> [16,256,2048], fp32 in/out.
// R4: NO LDS, NO BARRIERS. Each wave loads A/B fragments directly to
// registers in MFMA layout, converts fp32->bf16 in-reg, and runs an
// independent K-loop. Removes the barrier/vmcnt serialization that held
// R1-R3 at 44-50 us (all pipes <30% busy, 6600 cyc/iter vs ~400 of work).
// Block = 256 thr = 4 waves in 2x2 over a 128x128 block tile (L1/L2 reuse);
// wave tile 64x64 = 4x4 MFMAs of 16x16x32 bf16. grid (16,2,16) = 512 blocks.
#define NB 16
#define ND 256
#define NK 512
#define NT 2048
#define BK 32

typedef __attribute__((ext_vector_type(8))) short short8;
typedef __attribute__((ext_vector_type(4))) float f32x4;

union S8U { short8 v; unsigned int u[4]; };
union BF2U { __hip_bfloat162 h; unsigned int u; };

__device__ inline unsigned int pack2bf(float a, float b) {
    BF2U c; c.h = __float22bfloat162_rn(make_float2(a, b));
    return c.u;
}

__global__ __launch_bounds__(256, 2)  // ~190 live VGPR -> 2 waves/SIMD
void bmm_direct(const float* __restrict__ x, const float* __restrict__ path,
                float* __restrict__ out) {
    const int n0 = blockIdx.x * 128;
    const int m0 = blockIdx.y * 128;
    const int b  = blockIdx.z;
    const int lane = threadIdx.x & 63;
    const int wv   = threadIdx.x >> 6;
    const int wm   = (wv >> 1) * 64;   // wave row in block tile
    const int wn   = (wv & 1) * 64;    // wave col in block tile
    const int q    = lane >> 4;        // quad 0..3 -> k = q*8 + j
    const int lm   = lane & 15;        // m (A) / n (B) within fragment

    // A: lane lm = row, needs 8 consecutive k at q*8 (x is k-contiguous)
    const float* ag[4];
#pragma unroll
    for (int mt = 0; mt < 4; ++mt)
        ag[mt] = x + ((size_t)b * ND + (m0 + wm + mt * 16 + lm)) * NK + q * 8;
    // B: lane lm = col, needs 8 k-strided elements (stride NT)
    const float* bg[4];
#pragma unroll
    for (int nt = 0; nt < 4; ++nt)
        bg[nt] = path + ((size_t)b * NK + q * 8) * NT + (n0 + wn + nt * 16 + lm);

    f32x4 acc[4][4];
#pragma unroll
    for (int i = 0; i < 4; ++i)
#pragma unroll
        for (int j = 0; j < 4; ++j)
            acc[i][j] = (f32x4){0.f, 0.f, 0.f, 0.f};

#pragma unroll 1   // keep rolled: 40 independent loads/iter is ILP enough;
                   // full unroll would blow past 256 VGPR
    for (int kt = 0; kt < NK / BK; ++kt) {
        // ---- issue all 40 independent global loads for this K-tile
        float4 a0[4], a1[4];
#pragma unroll
        for (int mt = 0; mt < 4; ++mt) {
            a0[mt] = *reinterpret_cast<const float4*>(ag[mt]);
            a1[mt] = *reinterpret_cast<const float4*>(ag[mt] + 4);
        }
        float bv[4][8];
#pragma unroll
        for (int nt = 0; nt < 4; ++nt)
#pragma unroll
            for (int j = 0; j < 8; ++j)
                bv[nt][j] = bg[nt][(size_t)j * NT];

        // ---- convert to bf16 fragments (2 elems per v_cvt_pk)
        short8 af[4], bfr[4];
#pragma unroll
        for (int mt = 0; mt < 4; ++mt) {
            S8U s;
            s.u[0] = pack2bf(a0[mt].x, a0[mt].y);
            s.u[1] = pack2bf(a0[mt].z, a0[mt].w);
            s.u[2] = pack2bf(a1[mt].x, a1[mt].y);
            s.u[3] = pack2bf(a1[mt].z, a1[mt].w);
            af[mt] = s.v;
        }
#pragma unroll
        for (int nt = 0; nt < 4; ++nt) {
            S8U s;
            s.u[0] = pack2bf(bv[nt][0], bv[nt][1]);
            s.u[1] = pack2bf(bv[nt][2], bv[nt][3]);
            s.u[2] = pack2bf(bv[nt][4], bv[nt][5]);
            s.u[3] = pack2bf(bv[nt][6], bv[nt][7]);
            bfr[nt] = s.v;
        }

        // ---- 16 MFMAs
#pragma unroll
        for (int mt = 0; mt < 4; ++mt)
#pragma unroll
            for (int nt = 0; nt < 4; ++nt)
                acc[mt][nt] = __builtin_amdgcn_mfma_f32_16x16x32_bf16(
                    af[mt], bfr[nt], acc[mt][nt], 0, 0, 0);

        // ---- advance pointers
#pragma unroll
        for (int mt = 0; mt < 4; ++mt) ag[mt] += BK;
#pragma unroll
        for (int nt = 0; nt < 4; ++nt) bg[nt] += (size_t)BK * NT;
    }

    // ---- epilogue: C/D layout col=lane&15, row=(lane>>4)*4+reg [m89-verified]
    float* og = out + ((size_t)b * ND + (m0 + wm)) * NT + n0 + wn;
#pragma unroll
    for (int mt = 0; mt < 4; ++mt)
#pragma unroll
        for (int r = 0; r < 4; ++r) {
            int row = mt * 16 + q * 4 + r;
#pragma unroll
            for (int nt = 0; nt < 4; ++nt)
                og[(size_t)row * NT + nt * 16 + lm] = acc[mt][nt][r];
        }
}

extern "C" void kernel_launch(void* const* d_in, const int* in_sizes, int n_in,
                              void* d_out, int out_size, void* d_ws, size_t ws_size,
                              hipStream_t stream) {
    const float* x    = (const float*)d_in[0];   // [16, 256, 512]
    const float* path = (const float*)d_in[1];   // [16, 512, 2048]
    float* out        = (float*)d_out;           // [16, 256, 2048]
    dim3 grid(NT / 128, ND / 128, NB);           // (16, 2, 16) = 512 blocks
    dim3 block(256);
    bmm_direct<<<grid, block, 0, stream>>>(x, path, out);
}

// Round 5
// 122.144 us; speedup vs baseline: 1.8436x; 1.8436x over previous
//
#include <hip/hip_runtime.h>
#include <hip/hip_bf16.h>

// bmm [16,256,512] @ [16,512,2048] -> [16,256,2048], fp32 in/out.
// R5: back to LDS staging (R4 proved direct fragment loads are uncoalesced
// poison: 64 cache lines per A-load inst). R1 serial structure (~39us) +
// BK=64 (8 iters, 2x bytes/iter in flight), LDS double-buffer (1 barrier/iter),
// branch-free depth-1 prefetch (last iter peeled, no guards -> static vmcnt).
// 128x128 tile, 256 thr = 4 waves 2x2, wave tile 64x64 = 4x4 MFMAs x 2 k-chunks.
#define NB 16
#define ND 256
#define NK 512
#define NT 2048
#define BM 128
#define BN 128
#define BK 64
#define KITERS (NK / BK)  // 8
#define RSA 72   // A row stride (shorts): 144 B, mult-16 -> b128 frag reads, 2-way banks
#define RSB 68   // B row stride (shorts): 136 B, mult-8 -> b64 frag reads; write stride 34 dw (gcd 2)

typedef __attribute__((ext_vector_type(8))) short short8;
typedef __attribute__((ext_vector_type(4))) float f32x4;

union S8U { short8 v; uint2 u[2]; };
union BF2U { __hip_bfloat162 h; unsigned int u; };

__device__ inline unsigned int pack2bf(float a, float b) {
    BF2U c; c.h = __float22bfloat162_rn(make_float2(a, b));
    return c.u;
}

__global__ __launch_bounds__(256, 2)  // ~110 VGPR + 64 AGPR -> 2 waves/SIMD
void bmm_bf16_mfma(const float* __restrict__ x, const float* __restrict__ path,
                   float* __restrict__ out) {
    const int n0 = blockIdx.x * BN;
    const int m0 = blockIdx.y * BM;
    const int b  = blockIdx.z;
    const int t    = threadIdx.x;
    const int lane = t & 63;
    const int wv   = t >> 6;
    const int wm   = (wv >> 1) * 64;
    const int wn   = (wv & 1) * 64;
    const int q    = lane >> 4;
    const int lm   = lane & 15;

    __shared__ unsigned short As[2][BM * RSA];  // [m][k] bf16
    __shared__ unsigned short Bs[2][BN * RSB];  // [n][k] bf16 (transposed)

    const float* xg = x    + ((size_t)b * ND + m0) * NK;
    const float* pg = path + (size_t)b * NK * NT + n0;

    f32x4 acc[4][4];
#pragma unroll
    for (int i = 0; i < 4; ++i)
#pragma unroll
        for (int j = 0; j < 4; ++j)
            acc[i][j] = (f32x4){0.f, 0.f, 0.f, 0.f};

    // prefetch registers (single set, depth-1)
    float4 aR[8];    // A: 128x64 fp32 = 2048 float4 / 256 thr
    float  bR[32];   // B: 64 k-rows x 128 n / 256 thr (wave wv: k-rows wv*16..+15; lane: n=lane, lane+64)

#define LOAD_TILE(k0)                                                         \
    {                                                                         \
        _Pragma("unroll")                                                     \
        for (int i = 0; i < 8; ++i) {                                         \
            int f = t + i * 256;                                              \
            int row = f >> 4, c4 = f & 15;                                    \
            aR[i] = *reinterpret_cast<const float4*>(                         \
                xg + (size_t)row * NK + (k0) + c4 * 4);                       \
        }                                                                     \
        _Pragma("unroll")                                                     \
        for (int j = 0; j < 16; ++j) {                                        \
            const float* s = pg + (size_t)((k0) + wv * 16 + j) * NT + lane;   \
            bR[j]      = s[0];                                                \
            bR[16 + j] = s[64];                                               \
        }                                                                     \
    }

#define STORE_TILE(buf)                                                       \
    {                                                                         \
        _Pragma("unroll")                                                     \
        for (int i = 0; i < 8; ++i) {                                         \
            int f = t + i * 256;                                              \
            int row = f >> 4, c4 = f & 15;                                    \
            uint2 p;                                                          \
            p.x = pack2bf(aR[i].x, aR[i].y);                                  \
            p.y = pack2bf(aR[i].z, aR[i].w);                                  \
            *reinterpret_cast<uint2*>(&As[buf][row * RSA + c4 * 4]) = p;      \
        }                                                                     \
        _Pragma("unroll")                                                     \
        for (int g = 0; g < 4; ++g) {                                         \
            uint2 p0, p1;                                                     \
            p0.x = pack2bf(bR[4 * g + 0], bR[4 * g + 1]);                     \
            p0.y = pack2bf(bR[4 * g + 2], bR[4 * g + 3]);                     \
            p1.x = pack2bf(bR[16 + 4 * g + 0], bR[16 + 4 * g + 1]);           \
            p1.y = pack2bf(bR[16 + 4 * g + 2], bR[16 + 4 * g + 3]);           \
            *reinterpret_cast<uint2*>(&Bs[buf][lane * RSB + wv * 16 + 4 * g]) = p0; \
            *reinterpret_cast<uint2*>(&Bs[buf][(lane + 64) * RSB + wv * 16 + 4 * g]) = p1; \
        }                                                                     \
    }

#define MFMA_TILE(buf)                                                        \
    {                                                                         \
        _Pragma("unroll")                                                     \
        for (int kc = 0; kc < 2; ++kc) {                                      \
            short8 af[4], bfr[4];                                             \
            _Pragma("unroll")                                                 \
            for (int mt = 0; mt < 4; ++mt)                                    \
                af[mt] = *reinterpret_cast<const short8*>(                    \
                    &As[buf][(wm + mt * 16 + lm) * RSA + kc * 32 + q * 8]);   \
            _Pragma("unroll")                                                 \
            for (int nt = 0; nt < 4; ++nt) {                                  \
                S8U s;                                                        \
                const unsigned short* bp =                                    \
                    &Bs[buf][(wn + nt * 16 + lm) * RSB + kc * 32 + q * 8];    \
                s.u[0] = *reinterpret_cast<const uint2*>(bp);                 \
                s.u[1] = *reinterpret_cast<const uint2*>(bp + 4);             \
                bfr[nt] = s.v;                                                \
            }                                                                 \
            _Pragma("unroll")                                                 \
            for (int mt = 0; mt < 4; ++mt)                                    \
                _Pragma("unroll")                                             \
                for (int nt = 0; nt < 4; ++nt)                                \
                    acc[mt][nt] = __builtin_amdgcn_mfma_f32_16x16x32_bf16(    \
                        af[mt], bfr[nt], acc[mt][nt], 0, 0, 0);               \
        }                                                                     \
    }

    // prologue
    LOAD_TILE(0)
    STORE_TILE(0)
    __syncthreads();

    // iters 0..KITERS-2: branch-free (prefetch always valid)
#pragma unroll 1
    for (int it = 0; it < KITERS - 1; ++it) {
        LOAD_TILE((it + 1) * BK)       // issue next tile's loads first
        MFMA_TILE(it & 1)              // compute on current buffer
        STORE_TILE((it + 1) & 1)       // convert+store (waits on this iter's loads)
        __syncthreads();
    }
    // final iteration: compute only
    MFMA_TILE((KITERS - 1) & 1)

    // epilogue: C/D layout col=lane&15, row=(lane>>4)*4+reg  [m89-verified]
    float* og = out + ((size_t)b * ND + (m0 + wm)) * NT + n0 + wn;
#pragma unroll
    for (int mt = 0; mt < 4; ++mt)
#pragma unroll
        for (int r = 0; r < 4; ++r) {
            int row = mt * 16 + q * 4 + r;
#pragma unroll
            for (int nt = 0; nt < 4; ++nt)
                og[(size_t)row * NT + nt * 16 + lm] = acc[mt][nt][r];
        }
}

extern "C" void kernel_launch(void* const* d_in, const int* in_sizes, int n_in,
                              void* d_out, int out_size, void* d_ws, size_t ws_size,
                              hipStream_t stream) {
    const float* x    = (const float*)d_in[0];   // [16, 256, 512]
    const float* path = (const float*)d_in[1];   // [16, 512, 2048]
    float* out        = (float*)d_out;           // [16, 256, 2048]
    dim3 grid(NT / BN, ND / BM, NB);             // (16, 2, 16) = 512 blocks
    dim3 block(256);
    bmm_bf16_mfma<<<grid, block, 0, stream>>>(x, path, out);
}